// Round 2
// 133.295 us; speedup vs baseline: 1.0002x; 1.0002x over previous
//
#include <hip/hip_runtime.h>
#include <cmath>
#include <algorithm>

#ifndef M_PI
#define M_PI 3.14159265358979323846
#endif

// Problem constants (fixed by setup_inputs in the reference)
#define B_ 8
#define F_ 3
#define H_ 224
#define W_ 224
#define T_ 8          // ntau
#define A_ 12         // num_angles
#define NK 96         // T_*A_
#define STRIDE_ 2
#define HS_ 112
#define WS_ 112
#define PLANE_ (H_ * W_)        // 50176
#define SLICE_ (HS_ * WS_)      // 12544

#define RI 8          // output rows per block (was 4: halves setup+staging per row)
#define BANDROWS 78   // staged rows: 2*(RI-1) + group cy-range + 2 = 75 max (<=78)
#define PITCH 225     // LDS row pitch in dwords: E[0..111] | O[0..111] | 1 pad
#define HALF 112

// Per-offset constants (host, f64) reordered into two cy-sorted groups of 48
// so each group's row-band fits 70.2 KB LDS -> 2 blocks/CU (forced via
// __launch_bounds__(1024,8)). korig maps back to output k = t*A + a.
// Group 0 = all negative cy (-60..-1), group 1 = 0..59 -> band <= 75 rows.
// Per-offset (vs per-element f32) floor/frac is continuity-safe: validated
// in prior rounds, absmax 1.6e-2 << 9.3e-2.
struct LPArgs {
    int   cy[NK];  int cx[NK];
    float fy[NK];  float fx[NK];
    int   korig[NK];
    int   cymin[2]; int cymax[2];
};

static LPArgs make_args() {
    int cy[NK], cx[NK]; float fy[NK], fx[NK];
    double c = pow(60.0, 1.0 / 7.0) - 1.0;
    for (int t = 0; t < T_; ++t) {
        double tau = pow(1.0 + c, (double)t);
        for (int a = 0; a < A_; ++a) {
            double th = (double)a * (2.0 * M_PI / (double)A_) - M_PI;
            float yo = (float)(tau * sin(th)), xo = (float)(tau * cos(th));
            int k = t * A_ + a;
            float yf = floorf(yo), xf = floorf(xo);
            cy[k] = (int)yf; fy[k] = yo - yf;
            cx[k] = (int)xf; fx[k] = xo - xf;
        }
    }
    int idx[NK];
    for (int k = 0; k < NK; ++k) idx[k] = k;
    std::sort(idx, idx + NK, [&](int a, int b) { return cy[a] < cy[b]; });
    LPArgs r;
    r.cymin[0] = r.cymin[1] = 1000; r.cymax[0] = r.cymax[1] = -1000;
    for (int p = 0; p < NK; ++p) {
        int k = idx[p], g = p / 48;
        r.cy[p] = cy[k]; r.cx[p] = cx[k];
        r.fy[p] = fy[k]; r.fx[p] = fx[k];
        r.korig[p] = k;
        r.cymin[g] = std::min(r.cymin[g], cy[k]);
        r.cymax[g] = std::max(r.cymax[g], cy[k]);
    }
    return r;
}

// Grid (24 planes, 14 i-tiles, 2 cy-groups), block 1024 (16 waves),
// LDS 70.2 KB, launch_bounds(1024,8) forces VGPR<=64 -> 2 blocks/CU.
//
// LDS layout is even/odd-column DEINTERLEAVED per row (pitch 225 dwords):
//   row r: [E[c]=inp[r][2c] c=0..111 | O[c]=inp[r][2c+1] | pad]
// A bilinear x-pair {ix0, ix0+1} is always one even + one odd column, so
// each lane reads E at lane-stride-1 and O at lane-stride-1 -> zero bank
// conflicts (the old interleaved layout read at lane-stride-2 = 4-way
// conflict, 1.58x per m136). ds_read2_b32 offset1:225 (=PITCH, <=255 max)
// fetches both y-rows of each array in ONE instruction.
__global__ __launch_bounds__(1024, 8) void lp_sample_kernel(
    const float* __restrict__ inp, float* __restrict__ out, LPArgs args) {

    __shared__ float lds[BANDROWS * PITCH];   // 78*225*4 = 70,200 B

    const int bf = blockIdx.x;            // b*F + f
    const int i0 = blockIdx.y * RI;
    const int g  = blockIdx.z;

    const int r0 = max(0, 2 * i0 + args.cymin[g]);
    const int r1 = min(H_ - 1, 2 * i0 + 2 * (RI - 1) + args.cymax[g] + 1);
    const int nrows = min(r1 - r0 + 1, BANDROWS);   // defensive clamp

    const float* plane = inp + (size_t)bf * PLANE_;

    {   // staging with even/odd deinterleave: float4 {e,o,e,o} -> E-pair + O-pair
        const int n = nrows * (W_ / 4);   // <= 78*56 = 4368
        for (int v = threadIdx.x; v < n; v += 1024) {
            const unsigned r = (unsigned)v / 56u;       // compiler magic-div
            const int u = v - (int)r * 56;              // float4 index in row
            const float4 val = *(const float4*)(plane + (size_t)(r0 + (int)r) * W_ + 4 * u);
            float* rowp = lds + r * PITCH;
            const int e = 2 * u;
            rowp[e]            = val.x;   // col 4u   (even)
            rowp[e + 1]        = val.z;   // col 4u+2 (even)
            rowp[HALF + e]     = val.y;   // col 4u+1 (odd)
            rowp[HALF + e + 1] = val.w;   // col 4u+3 (odd)
        }
    }
    __syncthreads();

    const int lane = threadIdx.x & 63;
    const int wave = __builtin_amdgcn_readfirstlane(threadIdx.x >> 6);

    float* outp = out + (size_t)bf * (NK * SLICE_) + (size_t)i0 * WS_;

#pragma unroll 1
    for (int tt = 0; tt < 6; ++tt) {
        const int task = wave + (tt << 4);            // 0..95
        const int kl   = task >> 1;                   // 0..47 within group
        const int h    = task & 1;                    // column half
        const int kk   = g * 48 + kl;

        const int   cy = args.cy[kk]; const float fy = args.fy[kk];
        const int   cx = args.cx[kk]; const float fx = args.fx[kk];
        const int   ko = args.korig[kk];
        const int   P  = cx & 1;                      // x-pair parity (uniform)

        // --- per-task x-side setup (amortized over RI=8 rows) ---
        const int j   = h * 64 + lane;
        const int ix0 = 2 * j + cx;                   // true left column
        // contribution = wL*inp[ix0] (if in range) + wR*inp[ix0+1] (if in range)
        const float wLv = (ix0 >= 0  && ix0 <= W_ - 1) ? (1.0f - fx) : 0.0f;
        const float wRv = (ix0 >= -1 && ix0 <= W_ - 2) ? fx          : 0.0f;
        // even col = ix0+P, odd col = ix0+1-P (ix0 parity == P per lane)
        int eidx = (ix0 + P) >> 1;                    // arith shift; clamp below
        int oidx = (ix0 + 1 - P) >> 1;
        eidx = min(max(eidx, 0), HALF - 1);           // weights are 0 when clamped
        oidx = min(max(oidx, 0), HALF - 1);
        const float wE = P ? wRv : wLv;               // uniform select
        const float wO = P ? wLv : wRv;

        const float* eptr = lds + eidx;               // lane-stride-1 -> no conflicts
        const float* optr = lds + HALF + oidx;

        float* orow = outp + (size_t)ko * SLICE_ + j;

        if (j < WS_) {                                // mask idle lanes for whole loop
#pragma unroll 2
            for (int di = 0; di < RI; ++di) {
                const int iy0 = 2 * (i0 + di) + cy;   // wave-uniform
                float mA, mB;
                if (iy0 >= 0 && iy0 <= H_ - 2)  { mA = 1.0f - fy; mB = fy; }
                else if (iy0 == -1)             { mA = fy;        mB = 0.0f; }
                else if (iy0 == H_ - 1)         { mA = 0.0f;      mB = 1.0f - fy; }
                else                            { mA = 0.0f;      mB = 0.0f; }
                const int by = min(max(iy0, 0), H_ - 2);  // rows {by,by+1} staged
                const int rb = (by - r0) * PITCH;         // uniform

                // ds_read2_b32 offset0:0 offset1:225 x2 (conflict-free)
                const float e0 = eptr[rb], e1 = eptr[rb + PITCH];
                const float o0 = optr[rb], o1 = optr[rb + PITCH];

                const float rr = wE * (mA * e0 + mB * e1)
                               + wO * (mA * o0 + mB * o1);

                orow[(size_t)di * WS_] = rr;          // imm offset di*448
            }
        }
    }
}

extern "C" void kernel_launch(void* const* d_in, const int* in_sizes, int n_in,
                              void* d_out, int out_size, void* d_ws, size_t ws_size,
                              hipStream_t stream) {
    const float* inp = (const float*)d_in[0];
    float*       out = (float*)d_out;

    static const LPArgs args = make_args();   // host-side, once; capture-safe

    dim3 grid(B_ * F_, HS_ / RI, 2);          // 24 x 14 x 2
    lp_sample_kernel<<<grid, 1024, 0, stream>>>(inp, out, args);
}